// Round 7
// baseline (258.710 us; speedup 1.0000x reference)
//
#include <hip/hip_runtime.h>
#include <math.h>

typedef unsigned short u16;
typedef __attribute__((ext_vector_type(8))) short short8;   // 8 bf16 = 4 VGPRs
typedef __attribute__((ext_vector_type(4))) short short4v;  // 4 bf16 = 2 VGPRs
typedef __attribute__((ext_vector_type(4))) float f32x4;    // MFMA C/D frag

constexpr int Bn = 4, Sn = 2048, Dn = 1024, Hn = 16;
// softmax scale folded into K: kb stores K * (log2(e)/8)
constexpr float KSCL = 1.44269504f * 0.125f;

__device__ __forceinline__ u16 f2bf(float f) {  // RNE float->bf16
  unsigned u = __float_as_uint(f);
  u += 0x7fffu + ((u >> 16) & 1u);
  return (u16)(u >> 16);
}
__device__ __forceinline__ u16 f2bf_t(float f) {  // trunc (p>=0, tiny bias)
  return (u16)(__float_as_uint(f) >> 16);
}

__device__ __forceinline__ f32x4 mfma32(short8 a, short8 b, f32x4 c) {
  return __builtin_amdgcn_mfma_f32_16x16x32_bf16(a, b, c, 0, 0, 0);
}

// 16x16x16 bf16 MFMA (exists on gfx950 per ISA §10) w/ fallback chain.
__device__ __forceinline__ f32x4 mfma16(short4v a, short4v b, f32x4 c) {
#if __has_builtin(__builtin_amdgcn_mfma_f32_16x16x16_bf16)
  return __builtin_amdgcn_mfma_f32_16x16x16_bf16(a, b, c, 0, 0, 0);
#elif __has_builtin(__builtin_amdgcn_mfma_f32_16x16x16bf16_1k)
  return __builtin_amdgcn_mfma_f32_16x16x16bf16_1k(a, b, c, 0, 0, 0);
#else
  short8 a8 = {a[0], a[1], a[2], a[3], 0, 0, 0, 0};
  short8 b8 = {b[0], b[1], b[2], b[3], 0, 0, 0, 0};
  return __builtin_amdgcn_mfma_f32_16x16x32_bf16(a8, b8, c, 0, 0, 0);
#endif
}

__device__ __forceinline__ void gl_lds16(const u16* g, u16* l) {
  __builtin_amdgcn_global_load_lds(
      (const __attribute__((address_space(1))) unsigned int*)g,
      (__attribute__((address_space(3))) unsigned int*)l, 16, 0, 0);
}

// ---------------------------------------------------------------------------
__global__ __launch_bounds__(256) void cast_x(const float4* __restrict__ in,
                                              ushort4* __restrict__ out, int n4) {
  const int i = blockIdx.x * 256 + threadIdx.x;
  if (i < n4) {
    const float4 f = in[i];
    ushort4 o;
    o.x = f2bf(f.x); o.y = f2bf(f.y); o.z = f2bf(f.z); o.w = f2bf(f.w);
    out[i] = o;
  }
}

__global__ __launch_bounds__(256) void cast_w4(const float4* __restrict__ w0,
                                               const float4* __restrict__ w1,
                                               const float4* __restrict__ w2,
                                               const float4* __restrict__ w3,
                                               ushort4* __restrict__ o0,
                                               ushort4* __restrict__ o1,
                                               ushort4* __restrict__ o2,
                                               ushort4* __restrict__ o3) {
  const int z = blockIdx.y;
  const float4* in = z == 0 ? w0 : z == 1 ? w1 : z == 2 ? w2 : w3;
  ushort4* out = z == 0 ? o0 : z == 1 ? o1 : z == 2 ? o2 : o3;
  const int i = blockIdx.x * 256 + threadIdx.x;
  const float4 f = in[i];
  ushort4 o;
  o.x = f2bf(f.x); o.y = f2bf(f.y); o.z = f2bf(f.z); o.w = f2bf(f.w);
  out[i] = o;
}

// ---------------------------------------------------------------------------
// C[m,n] = sum_k A[m,k]*W[n,k], bf16 in. 128x128 tile, BK=32, 4 waves,
// global_load_lds w16, XOR chunk swizzle (2-way LDS frag reads).
// MODE 0: bf16 natural (scaled by `oscale`); MODE 1: f32 natural;
// MODE 2: bf16 into vt2 = V arranged in the attention PV A-frag layout
// (R4-verified: tile (b,h,jt64): elem [(hd)*64 + q*16 + mi*4 + e]).
// ---------------------------------------------------------------------------
template <int MODE>
__device__ __forceinline__ void gemm_body(const u16* __restrict__ A,
                                          const u16* __restrict__ W,
                                          u16* __restrict__ Cb,
                                          float* __restrict__ Cf,
                                          int bx, int by, float oscale) {
  __shared__ u16 Asm[128 * 32];
  __shared__ u16 Wsm[128 * 32];
  const int t = threadIdx.x;
  const int w = t >> 6, l = t & 63;
  const int wy = w >> 1, wx = w & 1;
  const int q = l >> 4, r = l & 15;
  const int m0 = bx * 128, n0 = by * 128;
  const int c0 = w * 64 + l;

  f32x4 acc[4][4] = {};

  for (int k0 = 0; k0 < 1024; k0 += 32) {
    __syncthreads();
#pragma unroll
    for (int i = 0; i < 2; ++i) {
      const int c = c0 + i * 256;
      const int row = c >> 2, cl = c & 3;
      const int cg = cl ^ ((row >> 1) & 3);
      gl_lds16(A + (size_t)(m0 + row) * 1024 + k0 + cg * 8, &Asm[c * 8]);
      gl_lds16(W + (size_t)(n0 + row) * 1024 + k0 + cg * 8, &Wsm[c * 8]);
    }
    __syncthreads();

    short8 af[4], bf[4];
#pragma unroll
    for (int mi = 0; mi < 4; ++mi) {
      const int rowA = wy * 64 + mi * 16 + r;
      af[mi] = *(const short8*)&Asm[rowA * 32 + (q ^ ((rowA >> 1) & 3)) * 8];
      const int rowB = wx * 64 + mi * 16 + r;
      bf[mi] = *(const short8*)&Wsm[rowB * 32 + (q ^ ((rowB >> 1) & 3)) * 8];
    }
#pragma unroll
    for (int mi = 0; mi < 4; ++mi)
#pragma unroll
      for (int ni = 0; ni < 4; ++ni)
        acc[mi][ni] = mfma32(af[mi], bf[ni], acc[mi][ni]);
  }

  if (MODE == 2) {
    // token = m0+wy*64+mi*16+q*4+e, feat(hd) = n0+wx*64+ni*16+r
    const int bq = m0 >> 11;
    const int jt = ((m0 & 2047) >> 6) + wy;   // 64-key tile index
    const int hh = (n0 >> 6) + wx;
    u16* vt_t = Cb + ((size_t)((bq * 16 + hh) * 32) + jt) * 4096;
#pragma unroll
    for (int mi = 0; mi < 4; ++mi)
#pragma unroll
      for (int ni = 0; ni < 4; ++ni) {
        short4v pk;
#pragma unroll
        for (int e = 0; e < 4; ++e) pk[e] = (short)f2bf(acc[mi][ni][e]);
        *(short4v*)&vt_t[(ni * 16 + r) * 64 + q * 16 + mi * 4] = pk;
      }
    return;
  }

#pragma unroll
  for (int mi = 0; mi < 4; ++mi) {
    const int row = m0 + wy * 64 + mi * 16 + q * 4;
#pragma unroll
    for (int ni = 0; ni < 4; ++ni) {
      const int col = n0 + wx * 64 + ni * 16 + r;
#pragma unroll
      for (int e = 0; e < 4; ++e) {
        if (MODE == 1)
          Cf[(size_t)(row + e) * 1024 + col] = acc[mi][ni][e];
        else
          Cb[(size_t)(row + e) * 1024 + col] = f2bf(acc[mi][ni][e] * oscale);
      }
    }
  }
}

// One launch for Q, K (scaled), V (vt2 layout): z = 0,1,2.
__global__ __launch_bounds__(256) void gemm_qkv(const u16* __restrict__ A,
                                                const u16* __restrict__ Wq,
                                                const u16* __restrict__ Wk,
                                                const u16* __restrict__ Wv,
                                                u16* __restrict__ Cq,
                                                u16* __restrict__ Ck,
                                                u16* __restrict__ Vt) {
  const int z = blockIdx.z;
  if (z == 0)
    gemm_body<0>(A, Wq, Cq, nullptr, blockIdx.x, blockIdx.y, 1.0f);
  else if (z == 1)
    gemm_body<0>(A, Wk, Ck, nullptr, blockIdx.x, blockIdx.y, KSCL);
  else
    gemm_body<2>(A, Wv, Vt, nullptr, blockIdx.x, blockIdx.y, 1.0f);
}

__global__ __launch_bounds__(256) void gemm_out(const u16* __restrict__ A,
                                                const u16* __restrict__ W,
                                                float* __restrict__ C) {
  gemm_body<1>(A, W, nullptr, C, blockIdx.x, blockIdx.y, 1.0f);
}

// ---------------------------------------------------------------------------
// Flash attention v6b: v6 with the K-fragment LDS index FIXED.
// Staging swizzle: chunk cl of row goes to slot cl ^ (row & 7); read of
// logical chunk (kf*4+q) for LDS row (hf*64+ni*16+r) is at slot
// ((kf*4+q) ^ (r & 7))  [since (hf*64+ni*16+r)&7 == r&7].
// 128-key K-tiles double-buffered; V frags direct from global vt2
// (L2-resident, XCD-pinned); register softmax; scale folded into kb.
// ---------------------------------------------------------------------------
__global__ __launch_bounds__(128, 2) void attn_v6(const u16* __restrict__ Qb,
                                                  const u16* __restrict__ Kb,
                                                  const u16* __restrict__ Vt,
                                                  u16* __restrict__ Ob) {
  const int i = blockIdx.x;                  // 0..1023
  const int grp = (i & 7) + 8 * (i >> 7);    // (b,h) group, pinned to XCD i&7
  const int qp = (i >> 3) & 15;              // 0..15 -> pair (qp, 31-qp)
  const int b = grp >> 4, h = grp & 15;
  const int t = threadIdx.x;
  const int w = t >> 6, l = t & 63;
  const int q = l >> 4, r = l & 15;

  __shared__ u16 Kd[2][128 * 64];  // 128-key tiles, chunk-swizzled

  const size_t kgbase = (size_t)(b * Sn) * Dn + h * 64;
  const size_t vgrp = (size_t)((b * Hn + h) * 32) * 4096;
  const f32x4 cz = {0.f, 0.f, 0.f, 0.f};

#pragma unroll 1
  for (int ph = 0; ph < 2; ++ph) {
    const int st = ph ? 31 - qp : qp;   // 64-row q-tile index
    const int ot_max = st >> 1;         // outer (128-key) tiles: 0..ot_max

    // Q B-frags (n = qrow = lane&15, k = hd = quad*8+j)
    short8 Qf[2][2];
#pragma unroll
    for (int mi = 0; mi < 2; ++mi)
#pragma unroll
      for (int kf = 0; kf < 2; ++kf)
        Qf[mi][kf] = *(const short8*)(Qb +
            (size_t)(b * Sn + st * 64 + w * 32 + mi * 16 + r) * Dn + h * 64 +
            kf * 32 + q * 8);

    f32x4 O[2][4] = {};
    float l_[2] = {0.f, 0.f};

    __syncthreads();  // prev phase readers done before restaging buf0
    // prologue: stage outer tile 0 -> buf 0  (1024 chunks / 128 thr = 8 each)
#pragma unroll
    for (int ii = 0; ii < 8; ++ii) {
      const int c = t + ii * 128;
      const int row = c >> 3, cl = c & 7;
      gl_lds16(Kb + kgbase + (size_t)row * Dn + (cl ^ (row & 7)) * 8,
               &Kd[0][c * 8]);
    }

    for (int jt = 0; jt <= ot_max; ++jt) {
      __syncthreads();  // tile jt staged (overlapped with prev iter compute)
      if (jt < ot_max) {  // prefetch outer tile jt+1
        const int nb = (jt + 1) & 1;
        const size_t krow0 = kgbase + (size_t)(jt + 1) * 128 * Dn;
#pragma unroll
        for (int ii = 0; ii < 8; ++ii) {
          const int c = t + ii * 128;
          const int row = c >> 3, cl = c & 7;
          gl_lds16(Kb + krow0 + (size_t)row * Dn + (cl ^ (row & 7)) * 8,
                   &Kd[nb][c * 8]);
        }
      }
      const u16* Kt = Kd[jt & 1];

#pragma unroll
      for (int hf = 0; hf < 2; ++hf) {       // two 64-key halves
        const int j64 = 2 * jt + hf;         // 64-key tile index
        if (j64 > st) break;                 // (uniform branch per block)

        // V A-frags direct from global (independent: issue early, L2 hides)
        const u16* vb = Vt + vgrp + (size_t)j64 * 4096;
        short8 Vg[8];
#pragma unroll
        for (int ni2 = 0; ni2 < 4; ++ni2)
#pragma unroll
          for (int kcp = 0; kcp < 2; ++kcp)
            Vg[ni2 * 2 + kcp] =
                *(const short8*)(vb + (ni2 * 16 + r) * 64 + q * 16 + kcp * 8);

        // S^T = K*Q^T (A=K from LDS, B=Q regs); scale pre-folded into K
        f32x4 S[2][4];
#pragma unroll
        for (int ni = 0; ni < 4; ++ni) {
          const int row = hf * 64 + ni * 16 + r;
          const short8 k0 = *(const short8*)&Kt[row * 64 + ((q) ^ (r & 7)) * 8];
          const short8 k1 = *(const short8*)&Kt[row * 64 + ((4 + q) ^ (r & 7)) * 8];
          S[0][ni] = mfma32(k0, Qf[0][0], cz);
          S[0][ni] = mfma32(k1, Qf[0][1], S[0][ni]);
          S[1][ni] = mfma32(k0, Qf[1][0], cz);
          S[1][ni] = mfma32(k1, Qf[1][1], S[1][ni]);
        }

        // causal mask on the diagonal 64-tile
        if (j64 == st) {
#pragma unroll
          for (int mi = 0; mi < 2; ++mi) {
            const int qrow = w * 32 + mi * 16 + r;
#pragma unroll
            for (int ni = 0; ni < 4; ++ni) {
              const int key = ni * 16 + q * 4;
#pragma unroll
              for (int e = 0; e < 4; ++e)
                if (key + e > qrow) S[mi][ni][e] = -3.0e38f;
            }
          }
        }

        // p = exp2(s) -> P^T B-frags in registers
        short4v Pf[2][4];
#pragma unroll
        for (int mi = 0; mi < 2; ++mi)
#pragma unroll
          for (int ni = 0; ni < 4; ++ni) {
            float p0 = __builtin_amdgcn_exp2f(S[mi][ni][0]);
            float p1 = __builtin_amdgcn_exp2f(S[mi][ni][1]);
            float p2 = __builtin_amdgcn_exp2f(S[mi][ni][2]);
            float p3 = __builtin_amdgcn_exp2f(S[mi][ni][3]);
            l_[mi] += (p0 + p1) + (p2 + p3);
            short4v pf = {(short)f2bf_t(p0), (short)f2bf_t(p1),
                          (short)f2bf_t(p2), (short)f2bf_t(p3)};
            Pf[mi][ni] = pf;
          }

        // O^T += V^T * P^T
#pragma unroll
        for (int ni2 = 0; ni2 < 4; ++ni2)
#pragma unroll
          for (int kcp = 0; kcp < 2; ++kcp) {
            const short8 vv = Vg[ni2 * 2 + kcp];
            const short4v va = {vv[0], vv[1], vv[2], vv[3]};
            const short4v vb2 = {vv[4], vv[5], vv[6], vv[7]};
            O[0][ni2] = mfma16(va, Pf[0][2 * kcp], O[0][ni2]);
            O[0][ni2] = mfma16(vb2, Pf[0][2 * kcp + 1], O[0][ni2]);
            O[1][ni2] = mfma16(va, Pf[1][2 * kcp], O[1][ni2]);
            O[1][ni2] = mfma16(vb2, Pf[1][2 * kcp + 1], O[1][ni2]);
          }
      }
    }

    // epilogue: reduce l over quads, scale, packed 8B stores
#pragma unroll
    for (int mi = 0; mi < 2; ++mi) {
      float s = l_[mi];
      s += __shfl_xor(s, 16, 64);
      s += __shfl_xor(s, 32, 64);
      const float rl = 1.0f / s;
#pragma unroll
      for (int ni2 = 0; ni2 < 4; ++ni2) {
        short4v o;
#pragma unroll
        for (int e = 0; e < 4; ++e) o[e] = (short)f2bf(O[mi][ni2][e] * rl);
        *(short4v*)(Ob + (size_t)(b * Sn + st * 64 + w * 32 + mi * 16 + r) * Dn +
                    h * 64 + ni2 * 16 + q * 4) = o;
      }
    }
  }
}

// ---------------------------------------------------------------------------
extern "C" void kernel_launch(void* const* d_in, const int* in_sizes, int n_in,
                              void* d_out, int out_size, void* d_ws, size_t ws_size,
                              hipStream_t stream) {
  const float* x  = (const float*)d_in[0];
  const float* wq = (const float*)d_in[1];
  const float* wk = (const float*)d_in[2];
  const float* wv = (const float*)d_in[3];
  const float* wo = (const float*)d_in[4];
  float* out = (float*)d_out;

  u16* xb  = (u16*)d_ws;            // 8M u16
  u16* wqb = xb + 8388608;
  u16* wkb = wqb + 1048576;
  u16* wvb = wkb + 1048576;
  u16* wob = wvb + 1048576;
  u16* qb  = wob + 1048576;         // 8M each
  u16* kb  = qb + 8388608;
  u16* vt2 = kb + 8388608;          // V in PV A-frag layout (R4-verified)
  u16* aob = vt2 + 8388608;

  cast_x<<<8192, 256, 0, stream>>>((const float4*)x, (ushort4*)xb, 2097152);
  cast_w4<<<dim3(1024, 4), 256, 0, stream>>>(
      (const float4*)wq, (const float4*)wk, (const float4*)wv, (const float4*)wo,
      (ushort4*)wqb, (ushort4*)wkb, (ushort4*)wvb, (ushort4*)wob);

  gemm_qkv<<<dim3(64, 8, 3), 256, 0, stream>>>(xb, wqb, wkb, wvb, qb, kb, vt2);

  attn_v6<<<1024, 128, 0, stream>>>(qb, kb, vt2, aob);

  gemm_out<<<dim3(64, 8), 256, 0, stream>>>(aob, wob, out);
}